// Round 2
// baseline (68.519 us; speedup 1.0000x reference)
//
#include <hip/hip_runtime.h>
#include <hip/hip_bf16.h>

// Fused recurrent net, 32x32x16 MFMA, register-resident activations.
// All matmuls as C^T = W * act^T (col = batch row = lane&31 everywhere).
// The C/D -> next-B operand remap is done in-register with
// v_permlane32_swap_b32 (lane-half exchange), no LDS round-trip.

typedef __bf16 bf16x8_t __attribute__((ext_vector_type(8)));
typedef float f32x16_t __attribute__((ext_vector_type(16)));
typedef float f32x4_t __attribute__((ext_vector_type(4)));
typedef unsigned int uintx4_t __attribute__((ext_vector_type(4)));

#define THREADS 512

// Frag-packed bf16 weight staging in LDS: frag (mt,ks) for lane l is 16 B at
// base + ((mt*NKS+ks)*64 + l)*16.  b128 reads at lane*16 -> conflict-free.
#define OFF_WIN2E 0          // 4mt x 8ks: 32 KB
#define OFF_WI2E 32768       // 4mt x 4ks: 16 KB
#define OFF_WE2I 49152       // 2mt x 8ks: 16 KB
#define OFF_WE2OUT 65536     // 4mt x 8ks: 32 KB
#define SMEM_TOTAL 98304

__device__ __forceinline__ f32x16_t mfma32(bf16x8_t a, bf16x8_t b, f32x16_t c) {
  return __builtin_amdgcn_mfma_f32_32x32x16_bf16(a, b, c, 0, 0, 0);
}

// v_permlane32_swap_b32: x[32+i] <-> y[i].  After: x = {X(0:31);Y(0:31)},
// y = {X(32:63);Y(32:63)} -- i.e. x gathers lane-half 0, y gathers half 1.
__device__ __forceinline__ void swap32(unsigned int& x, unsigned int& y) {
  asm("v_permlane32_swap_b32 %0, %1" : "+v"(x), "+v"(y));
}

__device__ __forceinline__ unsigned int pack2_relu(float a, float b) {
  unsigned short lo = __builtin_bit_cast(unsigned short, (__bf16)fmaxf(a, 0.f));
  unsigned short hi = __builtin_bit_cast(unsigned short, (__bf16)fmaxf(b, 0.f));
  return (unsigned int)lo | ((unsigned int)hi << 16);
}

// One C/D tile (32 batch x 32 features) -> two B-frags (features as k-steps
// of 16), relu applied.  C/D row = (reg&3)+8*(reg>>2)+4*(lane>>5);
// B-frag k = 8*(lane>>5)+j.
__device__ __forceinline__ void tile_to_bfrags(const f32x16_t& t, bf16x8_t& fa,
                                               bf16x8_t& fb) {
  unsigned int P0 = pack2_relu(t[0], t[1]);
  unsigned int P1 = pack2_relu(t[2], t[3]);
  unsigned int P2 = pack2_relu(t[4], t[5]);
  unsigned int P3 = pack2_relu(t[6], t[7]);
  unsigned int P4 = pack2_relu(t[8], t[9]);
  unsigned int P5 = pack2_relu(t[10], t[11]);
  unsigned int P6 = pack2_relu(t[12], t[13]);
  unsigned int P7 = pack2_relu(t[14], t[15]);
  swap32(P0, P2);  // -> d0 (k 0..1 per half), d2 (k 4..5)
  swap32(P1, P3);  // -> d1, d3
  swap32(P4, P6);  // k-step B
  swap32(P5, P7);
  fa = __builtin_bit_cast(bf16x8_t, (uintx4_t){P0, P1, P2, P3});
  fb = __builtin_bit_cast(bf16x8_t, (uintx4_t){P4, P5, P6, P7});
}

__device__ __forceinline__ bf16x8_t ldfrag(const char* smem, int off, int fi,
                                           int lane) {
  return *reinterpret_cast<const bf16x8_t*>(smem + off + (fi * 64 + lane) * 16);
}

template <int NMT, int NKS, int COLS>
__device__ __forceinline__ void stage_frags(const float* __restrict__ W,
                                            char* dst, int tid) {
  constexpr int SLOTS = NMT * NKS * 64;
#pragma unroll
  for (int it = 0; it < SLOTS / THREADS; ++it) {
    int slot = it * THREADS + tid;
    int lane = slot & 63;
    int fi = slot >> 6;
    int mt = fi / NKS, ks = fi % NKS;
    int cc = lane & 31, hh = lane >> 5;
    const float* src = W + (mt * 32 + cc) * COLS + ks * 16 + hh * 8;
    float4 v0 = *reinterpret_cast<const float4*>(src);
    float4 v1 = *reinterpret_cast<const float4*>(src + 4);
    bf16x8_t hv;
    hv[0] = (__bf16)v0.x; hv[1] = (__bf16)v0.y;
    hv[2] = (__bf16)v0.z; hv[3] = (__bf16)v0.w;
    hv[4] = (__bf16)v1.x; hv[5] = (__bf16)v1.y;
    hv[6] = (__bf16)v1.z; hv[7] = (__bf16)v1.w;
    *reinterpret_cast<bf16x8_t*>(dst + slot * 16) = hv;
  }
}

__global__ __launch_bounds__(THREADS, 2) void unet_fused(
    const float* __restrict__ x,
    const float* __restrict__ Win2E,
    const float* __restrict__ WI2E,
    const float* __restrict__ WE2I,
    const float* __restrict__ WE2Out,
    const int* __restrict__ Tptr,
    float* __restrict__ out) {
  extern __shared__ char smem[];
  const int tid = threadIdx.x;

  stage_frags<4, 8, 128>(Win2E, smem + OFF_WIN2E, tid);
  stage_frags<4, 4, 64>(WI2E, smem + OFF_WI2E, tid);
  stage_frags<2, 8, 128>(WE2I, smem + OFF_WE2I, tid);
  stage_frags<4, 8, 128>(WE2Out, smem + OFF_WE2OUT, tid);
  __syncthreads();

  const int wid = tid >> 6, lane = tid & 63;
  const int c = lane & 31, h = lane >> 5;
  const int T = *Tptr;
  const long row0 = ((long)blockIdx.x * 8 + wid) * 32;
  const f32x16_t Z = {};

  // x B-frags: lane reads 8 contiguous floats at feature ks*16 + h*8.
  bf16x8_t xb[8];
#pragma unroll
  for (int ks = 0; ks < 8; ++ks) {
    const float* xp = x + (row0 + c) * 128 + ks * 16 + h * 8;
    float4 v0 = *reinterpret_cast<const float4*>(xp);
    float4 v1 = *reinterpret_cast<const float4*>(xp + 4);
    bf16x8_t hv;
    hv[0] = (__bf16)v0.x; hv[1] = (__bf16)v0.y;
    hv[2] = (__bf16)v0.z; hv[3] = (__bf16)v0.w;
    hv[4] = (__bf16)v1.x; hv[5] = (__bf16)v1.y;
    hv[6] = (__bf16)v1.z; hv[7] = (__bf16)v1.w;
    xb[ks] = hv;
  }

  // ff^T = Win2E * x^T, f32 for the whole kernel.
  f32x16_t ff[4];
#pragma unroll
  for (int mt = 0; mt < 4; ++mt)
    ff[mt] = mfma32(ldfrag(smem, OFF_WIN2E, mt * 8 + 0, lane), xb[0], Z);
#pragma unroll
  for (int ks = 1; ks < 8; ++ks)
#pragma unroll
    for (int mt = 0; mt < 4; ++mt)
      ff[mt] = mfma32(ldfrag(smem, OFF_WIN2E, mt * 8 + ks, lane), xb[ks], ff[mt]);

  f32x16_t acc_e[4];
#pragma unroll
  for (int mt = 0; mt < 4; ++mt) acc_e[mt] = ff[mt];  // step 0: actI = 0

  bf16x8_t eb[8];
  for (int t = 0;; ++t) {
    // actE = relu(acc_e) -> B-frags, in-register.
#pragma unroll
    for (int mt = 0; mt < 4; ++mt)
      tile_to_bfrags(acc_e[mt], eb[2 * mt], eb[2 * mt + 1]);
    if (t == T - 1) break;  // last step's actI is dead

    // actI^T = relu(WE2I * actE^T)
    f32x16_t acc_i[2];
#pragma unroll
    for (int mt = 0; mt < 2; ++mt)
      acc_i[mt] = mfma32(ldfrag(smem, OFF_WE2I, mt * 8 + 0, lane), eb[0], Z);
#pragma unroll
    for (int ks = 1; ks < 8; ++ks)
#pragma unroll
      for (int mt = 0; mt < 2; ++mt)
        acc_i[mt] =
            mfma32(ldfrag(smem, OFF_WE2I, mt * 8 + ks, lane), eb[ks], acc_i[mt]);

    bf16x8_t ib[4];
#pragma unroll
    for (int mt = 0; mt < 2; ++mt)
      tile_to_bfrags(acc_i[mt], ib[2 * mt], ib[2 * mt + 1]);

    // next acc_e = ff + WI2E * actI^T
#pragma unroll
    for (int mt = 0; mt < 4; ++mt)
      acc_e[mt] = mfma32(ldfrag(smem, OFF_WI2E, mt * 4 + 0, lane), ib[0], ff[mt]);
#pragma unroll
    for (int ks = 1; ks < 4; ++ks)
#pragma unroll
      for (int mt = 0; mt < 4; ++mt)
        acc_e[mt] =
            mfma32(ldfrag(smem, OFF_WI2E, mt * 4 + ks, lane), ib[ks], acc_e[mt]);
  }

  // out^T = relu(WE2Out * actE_last^T); f32x4 stores (4 consecutive features).
#pragma unroll
  for (int mt = 0; mt < 4; ++mt) {
    f32x16_t o = mfma32(ldfrag(smem, OFF_WE2OUT, mt * 8 + 0, lane), eb[0], Z);
#pragma unroll
    for (int ks = 1; ks < 8; ++ks)
      o = mfma32(ldfrag(smem, OFF_WE2OUT, mt * 8 + ks, lane), eb[ks], o);
#pragma unroll
    for (int q = 0; q < 4; ++q) {
      f32x4_t r;
#pragma unroll
      for (int s = 0; s < 4; ++s) r[s] = fmaxf(o[4 * q + s], 0.f);
      *reinterpret_cast<f32x4_t*>(out + (row0 + c) * 128 + mt * 32 + q * 8 +
                                  4 * h) = r;
    }
  }
}

extern "C" void kernel_launch(void* const* d_in, const int* in_sizes, int n_in,
                              void* d_out, int out_size, void* d_ws,
                              size_t ws_size, hipStream_t stream) {
  const float* x = (const float*)d_in[0];
  const float* Win2E = (const float*)d_in[1];
  const float* WI2E = (const float*)d_in[2];
  const float* WE2I = (const float*)d_in[3];
  const float* WE2Out = (const float*)d_in[4];
  const int* Tptr = (const int*)d_in[5];
  float* out = (float*)d_out;
  (void)n_in; (void)out_size; (void)d_ws; (void)ws_size;

  const int B = in_sizes[0] / 128;  // 131072
  (void)hipFuncSetAttribute(reinterpret_cast<const void*>(unet_fused),
                            hipFuncAttributeMaxDynamicSharedMemorySize,
                            SMEM_TOTAL);
  dim3 grid(B / 256), block(THREADS);
  unet_fused<<<grid, block, SMEM_TOTAL, stream>>>(x, Win2E, WI2E, WE2I, WE2Out,
                                                  Tptr, out);
}